// Round 1
// baseline (41107.245 us; speedup 1.0000x reference)
//
#include <hip/hip_runtime.h>

// ---------------------------------------------------------------------------
// 2-layer LSTM, T=512 B=32 I=512 H=1024.
// Strategy: ONE persistent kernel, 256 WGs x 512 threads (8 waves), layer-
// pipelined over 513 wall-steps (layer0@t=s  ||  layer1@t=s-1).
// All weights bf16 in LDS (per-WG slice of 16 gate rows: 4 hidden dims x
// {i,f,g,o}, both layers, x-projections folded into the K dimension).
// Grid barrier: per-WG flag + all-to-all poll (1 dwordx4-equivalent per lane).
// ---------------------------------------------------------------------------

typedef unsigned short u16;
typedef __attribute__((ext_vector_type(8))) __bf16 bf16x8;
typedef __attribute__((ext_vector_type(4))) float f32x4;
typedef __attribute__((ext_vector_type(4))) unsigned int u32x4;

#define HN_OFF 16777216   // 512*32*1024
#define CN_OFF 16842752   // HN_OFF + 2*32*1024

__device__ __forceinline__ u16 f2bf(float f) {   // RNE f32 -> bf16 (finite inputs)
  unsigned u = __builtin_bit_cast(unsigned, f);
  u += 0x7FFFu + ((u >> 16) & 1u);
  return (u16)(u >> 16);
}
__device__ __forceinline__ float sgm(float x) { return 1.f / (1.f + __expf(-x)); }

__device__ __forceinline__ bf16x8 ld_g16(const u16* p) {          // global 16B
  u32x4 v = *reinterpret_cast<const u32x4*>(p);
  return __builtin_bit_cast(bf16x8, v);
}
__device__ __forceinline__ bf16x8 ld_s16(const char* p) {         // LDS 16B
  u32x4 v = *reinterpret_cast<const u32x4*>(p);
  return __builtin_bit_cast(bf16x8, v);
}
__device__ __forceinline__ f32x4 mfma16(bf16x8 a, bf16x8 b, f32x4 c) {
  return __builtin_amdgcn_mfma_f32_16x16x32_bf16(a, b, c, 0, 0, 0);
}

// ---- layer0 K-chunks: c<32 -> h0_prev @ Whh0 (K=1024); c in [32,48) -> x[t] @ Wxh0 (K=512)
template <int C0, int C1>
__device__ __forceinline__ void chunks_L0(const u16* __restrict__ h0p,
                                          const u16* __restrict__ xbt,
                                          const char* wlds, int lane,
                                          f32x4& acc0, f32x4& acc1) {
  const int r = lane & 15;             // M-row (batch) / B-col (gate row)
  const int kq = (lane >> 4) * 8;      // k sub-offset within 32-chunk
  const int swz = (r & 7) << 4;
#pragma unroll
  for (int c = C0; c < C1; ++c) {
    const u16* a0p;
    const u16* a1p;
    if (c < 32) { a0p = h0p + r * 1024 + c * 32 + kq; a1p = a0p + 16 * 1024; }
    else        { a0p = xbt + r * 512 + (c - 32) * 32 + kq; a1p = a0p + 16 * 512; }
    bf16x8 a0 = ld_g16(a0p);
    bf16x8 a1 = ld_g16(a1p);
    bf16x8 bw = ld_s16(wlds + r * 3072 + ((c * 64 + kq * 2) ^ swz));
    acc0 = mfma16(a0, bw, acc0);
    acc1 = mfma16(a1, bw, acc1);
  }
}

// ---- layer1 K-chunks: c<32 -> h1_prev @ Whh1; c in [32,64) -> h0_prev(=hs0[t1]) @ Wxh1
template <int C0, int C1>
__device__ __forceinline__ void chunks_L1(const u16* __restrict__ h1p,
                                          const u16* __restrict__ h0p,
                                          const char* wlds, int lane,
                                          f32x4& acc0, f32x4& acc1) {
  const int r = lane & 15;
  const int kq = (lane >> 4) * 8;
  const int swz = (r & 7) << 4;
#pragma unroll
  for (int c = C0; c < C1; ++c) {
    const u16* base = (c < 32) ? (h1p + c * 32) : (h0p + (c - 32) * 32);
    const u16* a0p = base + r * 1024 + kq;
    bf16x8 a0 = ld_g16(a0p);
    bf16x8 a1 = ld_g16(a0p + 16 * 1024);
    bf16x8 bw = ld_s16(wlds + r * 4096 + ((c * 64 + kq * 2) ^ swz));
    acc0 = mfma16(a0, bw, acc0);
    acc1 = mfma16(a1, bw, acc1);
  }
}

// LDS layout (dynamic, 131200 B):
//   [0,      49152)  w0: 16 rows x 1536 bf16  = [Whh0 row | Wxh0 row], XOR-swizzled
//   [49152, 114688)  w1: 16 rows x 2048 bf16  = [Whh1 row | Wxh1 row], XOR-swizzled
//   [114688,131072)  part[8][32][16] f32 partial sums
//   [131072,131136)  bias0[16];  [131136,131200) bias1[16]
__global__ __launch_bounds__(512, 2) void lstm_fused(
    const u16* __restrict__ xbf, const u16* __restrict__ whh0,
    const u16* __restrict__ wxh0, const u16* __restrict__ whh1,
    const u16* __restrict__ wxh1, const float* __restrict__ bxh0,
    const float* __restrict__ bhh0, const float* __restrict__ bxh1,
    const float* __restrict__ bhh1, u16* __restrict__ h0buf,
    u16* __restrict__ h1buf, int* __restrict__ flags,
    float* __restrict__ out) {
  extern __shared__ char smem[];
  auto part = reinterpret_cast<float(*)[32][16]>(smem + 114688);
  float* bias0 = reinterpret_cast<float*>(smem + 131072);
  float* bias1 = reinterpret_cast<float*>(smem + 131136);

  const int tid = threadIdx.x;
  const int wg = blockIdx.x;
  const int wid = tid >> 6, lane = tid & 63;

  // ---- load this WG's 16 gate rows (n = gate*4 + jj -> global row gate*1024 + wg*4 + jj)
  for (int g = tid; g < 3072; g += 512) {          // w0: 16B granules
    int n = g / 192, gb = (g % 192) * 16, kcat = gb >> 1;
    int gr = ((n >> 2) << 10) + (wg << 2) + (n & 3);
    const u16* src = (kcat < 1024) ? (whh0 + gr * 1024 + kcat)
                                   : (wxh0 + gr * 512 + (kcat - 1024));
    *reinterpret_cast<u32x4*>(smem + n * 3072 + (gb ^ ((n & 7) << 4))) =
        *reinterpret_cast<const u32x4*>(src);
  }
  for (int g = tid; g < 4096; g += 512) {          // w1
    int n = g / 256, gb = (g % 256) * 16, kcat = gb >> 1;
    int gr = ((n >> 2) << 10) + (wg << 2) + (n & 3);
    const u16* src = (kcat < 1024) ? (whh1 + gr * 1024 + kcat)
                                   : (wxh1 + gr * 1024 + (kcat - 1024));
    *reinterpret_cast<u32x4*>(smem + 49152 + n * 4096 + (gb ^ ((n & 7) << 4))) =
        *reinterpret_cast<const u32x4*>(src);
  }
  if (tid < 16) {
    int gr = ((tid >> 2) << 10) + (wg << 2) + (tid & 3);
    bias0[tid] = bxh0[gr] + bhh0[gr];
    bias1[tid] = bxh1[gr] + bhh1[gr];
  }
  __syncthreads();

  float c0 = 0.f, c1 = 0.f;                 // cell state, register-resident
  const int jcol = (wg << 2) + (tid & 3);   // this thread's hidden column (reduce phase)

  for (int s = 0; s <= 512; ++s) {
    const u16* h0p = h0buf + (s & 1) * 32768;
    u16* h0n = h0buf + ((s + 1) & 1) * 32768;
    const u16* h1p = h1buf + (s & 1) * 32768;
    u16* h1n = h1buf + ((s + 1) & 1) * 32768;

    f32x4 acc0 = {0.f, 0.f, 0.f, 0.f}, acc1 = {0.f, 0.f, 0.f, 0.f};
    const bool act = (wid < 4) ? (s < 512) : (s >= 1);
    if (act) {
      const u16* xbt = xbf + s * 16384;
      if      (wid == 0) chunks_L0<0, 12>(h0p, xbt, smem, lane, acc0, acc1);
      else if (wid == 1) chunks_L0<12, 24>(h0p, xbt, smem, lane, acc0, acc1);
      else if (wid == 2) chunks_L0<24, 36>(h0p, xbt, smem, lane, acc0, acc1);
      else if (wid == 3) chunks_L0<36, 48>(h0p, xbt, smem, lane, acc0, acc1);
      else if (wid == 4) chunks_L1<0, 16>(h1p, h0p, smem + 49152, lane, acc0, acc1);
      else if (wid == 5) chunks_L1<16, 32>(h1p, h0p, smem + 49152, lane, acc0, acc1);
      else if (wid == 6) chunks_L1<32, 48>(h1p, h0p, smem + 49152, lane, acc0, acc1);
      else               chunks_L1<48, 64>(h1p, h0p, smem + 49152, lane, acc0, acc1);
      const int n = lane & 15, br = (lane >> 4) * 4;
#pragma unroll
      for (int j = 0; j < 4; ++j) {
        part[wid][br + j][n] = acc0[j];        // D-frag: col=lane&15, row=(lane>>4)*4+j
        part[wid][br + j + 16][n] = acc1[j];
      }
    }
    __syncthreads();

    if (tid < 128) {                 // ---- layer0 gate math (t0 = s)
      if (s < 512) {
        const int b = tid >> 2, jj = tid & 3;
        float gs[4];
#pragma unroll
        for (int gi = 0; gi < 4; ++gi) {
          const int n = gi * 4 + jj;
          gs[gi] = part[0][b][n] + part[1][b][n] + part[2][b][n] + part[3][b][n] + bias0[n];
        }
        c0 = sgm(gs[1]) * c0 + sgm(gs[0]) * tanhf(gs[2]);
        const float h = sgm(gs[3]) * tanhf(c0);
        h0n[b * 1024 + jcol] = f2bf(h);
        if (s == 511) {
          out[HN_OFF + b * 1024 + jcol] = h;
          out[CN_OFF + b * 1024 + jcol] = c0;
        }
      }
    } else if (tid < 256) {          // ---- layer1 gate math (t1 = s-1)
      if (s >= 1) {
        const int b = (tid - 128) >> 2, jj = tid & 3;
        float gs[4];
#pragma unroll
        for (int gi = 0; gi < 4; ++gi) {
          const int n = gi * 4 + jj;
          gs[gi] = part[4][b][n] + part[5][b][n] + part[6][b][n] + part[7][b][n] + bias1[n];
        }
        c1 = sgm(gs[1]) * c1 + sgm(gs[0]) * tanhf(gs[2]);
        const float h = sgm(gs[3]) * tanhf(c1);
        h1n[b * 1024 + jcol] = f2bf(h);
        const int t1 = s - 1;
        out[t1 * 32768 + b * 1024 + jcol] = h;
        if (t1 == 511) {
          out[HN_OFF + 32768 + b * 1024 + jcol] = h;
          out[CN_OFF + 32768 + b * 1024 + jcol] = c1;
        }
      }
    }

    if (s == 512) break;             // last step: no successor, skip barrier

    // ---- grid barrier: release h writes, flag, all-to-all poll, acquire
    __threadfence();
    __syncthreads();
    if (tid == 0)
      __hip_atomic_store(&flags[wg], s + 1, __ATOMIC_RELAXED, __HIP_MEMORY_SCOPE_AGENT);
    if (wid == 0) {
      const int i0 = lane * 4;
      for (;;) {
        int f0 = __hip_atomic_load(&flags[i0 + 0], __ATOMIC_RELAXED, __HIP_MEMORY_SCOPE_AGENT);
        int f1 = __hip_atomic_load(&flags[i0 + 1], __ATOMIC_RELAXED, __HIP_MEMORY_SCOPE_AGENT);
        int f2 = __hip_atomic_load(&flags[i0 + 2], __ATOMIC_RELAXED, __HIP_MEMORY_SCOPE_AGENT);
        int f3 = __hip_atomic_load(&flags[i0 + 3], __ATOMIC_RELAXED, __HIP_MEMORY_SCOPE_AGENT);
        if (__all((f0 > s) && (f1 > s) && (f2 > s) && (f3 > s))) break;
      }
    }
    __syncthreads();
    __threadfence();
  }
}

__global__ void cvt_bf16(const float* __restrict__ s, u16* __restrict__ d, int n) {
  int i = (blockIdx.x * blockDim.x + threadIdx.x) * 4;
  const int stride = gridDim.x * blockDim.x * 4;
  typedef __attribute__((ext_vector_type(4))) u16 u16x4;
  for (; i < n; i += stride) {
    f32x4 v = *reinterpret_cast<const f32x4*>(s + i);
    u16x4 o;
    o[0] = f2bf(v[0]); o[1] = f2bf(v[1]); o[2] = f2bf(v[2]); o[3] = f2bf(v[3]);
    *reinterpret_cast<u16x4*>(d + i) = o;
  }
}

// ws layout (bytes): xbf 0..16M | whh0 16M.. | wxh0 24M+1M.. | whh1 | wxh1 |
//                    h0buf 46137344 | h1buf 46268416 | flags 46399488
extern "C" void kernel_launch(void* const* d_in, const int* in_sizes, int n_in,
                              void* d_out, int out_size, void* d_ws, size_t ws_size,
                              hipStream_t stream) {
  const float* x    = (const float*)d_in[0];
  const float* Wxh0 = (const float*)d_in[1];
  const float* bxh0 = (const float*)d_in[2];
  const float* Whh0 = (const float*)d_in[3];
  const float* bhh0 = (const float*)d_in[4];
  const float* Wxh1 = (const float*)d_in[5];
  const float* bxh1 = (const float*)d_in[6];
  const float* Whh1 = (const float*)d_in[7];
  const float* bhh1 = (const float*)d_in[8];
  char* ws = (char*)d_ws;
  u16* xbf   = (u16*)(ws);
  u16* whh0b = (u16*)(ws + 16777216);
  u16* wxh0b = (u16*)(ws + 25165824);
  u16* whh1b = (u16*)(ws + 29360128);
  u16* wxh1b = (u16*)(ws + 37748736);
  u16* h0buf = (u16*)(ws + 46137344);
  u16* h1buf = (u16*)(ws + 46268416);
  int* flags = (int*)(ws + 46399488);

  cvt_bf16<<<1024, 256, 0, stream>>>(x, xbf, 512 * 32 * 512);
  cvt_bf16<<<1024, 256, 0, stream>>>(Whh0, whh0b, 4096 * 1024);
  cvt_bf16<<<512, 256, 0, stream>>>(Wxh0, wxh0b, 4096 * 512);
  cvt_bf16<<<1024, 256, 0, stream>>>(Whh1, whh1b, 4096 * 1024);
  cvt_bf16<<<1024, 256, 0, stream>>>(Wxh1, wxh1b, 4096 * 1024);
  (void)hipMemsetAsync(ws + 46137344, 0, 262144 + 1024, stream);  // h bufs + flags

  (void)hipFuncSetAttribute(reinterpret_cast<const void*>(lstm_fused),
                            hipFuncAttributeMaxDynamicSharedMemorySize, 131200);
  lstm_fused<<<dim3(256), dim3(512), 131200, stream>>>(
      xbf, whh0b, wxh0b, whh1b, wxh1b, bxh0, bhh0, bxh1, bhh1,
      h0buf, h1buf, flags, (float*)d_out);
}

// Round 2
// 4729.730 us; speedup vs baseline: 8.6912x; 8.6912x over previous
//
#include <hip/hip_runtime.h>

// ---------------------------------------------------------------------------
// 2-layer LSTM, T=512 B=32 I=512 H=1024 — persistent kernel, layer-pipelined.
// R2: NO __threadfence (the R1 killer: agent fences => buffer_wbl2/inv walk of
// the 4MiB XCD L2, ~80us/step). Coherence instead via:
//   - write-once h sequence buffers (h0seq/h1seq, one 64KB slot per step):
//     consumers use NORMAL cached loads (address written exactly once before
//     any read -> no staleness, L2-shared across the XCD's 32 WGs)
//   - producers store h with inline-asm sc0|sc1 (bypass L1/L2, ack at L3),
//     drained by s_waitcnt vmcnt(0) before the flag
//   - flags: relaxed agent-scope atomics (hardware sc1), 64B-padded, all-wave
//     all-to-all poll
// Layer pipeline: wall-step s computes L0@t=s and L1@t=s-1 (513 steps).
// Weights bf16 in LDS (16 gate rows/WG, x-projection folded into K).
// ---------------------------------------------------------------------------

typedef unsigned short u16;
typedef __attribute__((ext_vector_type(8))) __bf16 bf16x8;
typedef __attribute__((ext_vector_type(8))) u16 u16x8;
typedef __attribute__((ext_vector_type(4))) float f32x4;
typedef __attribute__((ext_vector_type(4))) unsigned int u32x4;

#define HN_OFF 16777216   // 512*32*1024
#define CN_OFF 16842752   // HN_OFF + 2*32*1024

__device__ __forceinline__ u16 f2bf(float f) {   // RNE f32 -> bf16 (finite)
  unsigned u = __builtin_bit_cast(unsigned, f);
  u += 0x7FFFu + ((u >> 16) & 1u);
  return (u16)(u >> 16);
}
__device__ __forceinline__ float sgm(float x) { return 1.f / (1.f + __expf(-x)); }
__device__ __forceinline__ float tnh(float x) { return 2.f / (1.f + __expf(-2.f * x)) - 1.f; }

__device__ __forceinline__ bf16x8 ld16(const u16* p) {            // normal cached 16B
  u32x4 v = *reinterpret_cast<const u32x4*>(p);
  return __builtin_bit_cast(bf16x8, v);
}
__device__ __forceinline__ bf16x8 lds16(const char* p) {
  u32x4 v = *reinterpret_cast<const u32x4*>(p);
  return __builtin_bit_cast(bf16x8, v);
}
__device__ __forceinline__ f32x4 mfma16(bf16x8 a, bf16x8 b, f32x4 c) {
  return __builtin_amdgcn_mfma_f32_16x16x32_bf16(a, b, c, 0, 0, 0);
}
__device__ __forceinline__ void st_h_coh(u16* p, float h) {       // bypass L1/L2
  unsigned v = f2bf(h);
  asm volatile("global_store_short %0, %1, off sc0 sc1" :: "v"(p), "v"(v) : "memory");
}

// One K-chunk group: A (global, normal loads) x W (LDS, swizzled) -> 2 MFMAs.
// CB = chunk index of A's k=0; LDB = LDS row stride in bytes.
template <int C0, int C1, int CB, int LDB>
__device__ __forceinline__ void chunks(const u16* __restrict__ A, int lda,
                                       const char* wlds, int lane,
                                       f32x4& acc0, f32x4& acc1) {
  const int r = lane & 15;
  const int kq = (lane >> 4) * 8;
  const int swz = (r & 7) << 4;
#pragma unroll
  for (int c = C0; c < C1; ++c) {
    const u16* ap = A + r * lda + (c - CB) * 32 + kq;
    bf16x8 a0 = ld16(ap);
    bf16x8 a1 = ld16(ap + 16 * lda);
    bf16x8 bw = lds16(wlds + r * LDB + ((c * 64 + kq * 2) ^ swz));
    acc0 = mfma16(a0, bw, acc0);
    acc1 = mfma16(a1, bw, acc1);
  }
}

__device__ __forceinline__ void pollwait(const int* flags, int lane, int s) {
  for (;;) {
    int f0 = __hip_atomic_load(flags + lane * 16,         __ATOMIC_RELAXED, __HIP_MEMORY_SCOPE_AGENT);
    int f1 = __hip_atomic_load(flags + (lane + 64) * 16,  __ATOMIC_RELAXED, __HIP_MEMORY_SCOPE_AGENT);
    int f2 = __hip_atomic_load(flags + (lane + 128) * 16, __ATOMIC_RELAXED, __HIP_MEMORY_SCOPE_AGENT);
    int f3 = __hip_atomic_load(flags + (lane + 192) * 16, __ATOMIC_RELAXED, __HIP_MEMORY_SCOPE_AGENT);
    if (__all((f0 >= s) & (f1 >= s) & (f2 >= s) & (f3 >= s))) break;
  }
}

// LDS (dynamic, 140928 B):
//   [0,      49152)  w0: 16 rows x 1536 bf16 [Whh0|Wxh0], XOR-swizzled
//   [49152, 114688)  w1: 16 rows x 2048 bf16 [Whh1|Wxh1], XOR-swizzled
//   [114688,140800)  part[12][32][17] f32 (L0: 0-3, L1: 4-11; 17 = +1 pad)
//   [140800,140864)  bias0[16]; [140864,140928) bias1[16]
__global__ __launch_bounds__(512, 2) void lstm_fused(
    const u16* __restrict__ xbf,
    const float* __restrict__ Whh0, const float* __restrict__ Wxh0,
    const float* __restrict__ Whh1, const float* __restrict__ Wxh1,
    const float* __restrict__ bxh0, const float* __restrict__ bhh0,
    const float* __restrict__ bxh1, const float* __restrict__ bhh1,
    u16* __restrict__ h0seq, u16* __restrict__ h1seq,
    int* __restrict__ flags, float* __restrict__ out) {
  extern __shared__ char smem[];
  auto part = reinterpret_cast<float(*)[32][17]>(smem + 114688);
  float* bias0 = reinterpret_cast<float*>(smem + 140800);
  float* bias1 = reinterpret_cast<float*>(smem + 140864);
  const char* w0 = smem;
  const char* w1 = smem + 49152;

  const int tid = threadIdx.x;
  const int wg = blockIdx.x;
  const int wid = tid >> 6, lane = tid & 63;

  // ---- LDS weight fill, f32 -> bf16 inline (rows n: gate*4+jj -> global gate*1024+wg*4+jj)
  for (int g = tid; g < 3072; g += 512) {
    int n = g / 192, gi = g % 192, kc = gi * 8;
    int gr = ((n >> 2) << 10) + (wg << 2) + (n & 3);
    const float* src = (kc < 1024) ? (Whh0 + gr * 1024 + kc) : (Wxh0 + gr * 512 + (kc - 1024));
    f32x4 lo = *reinterpret_cast<const f32x4*>(src);
    f32x4 hi = *reinterpret_cast<const f32x4*>(src + 4);
    u16x8 o;
    o[0]=f2bf(lo[0]); o[1]=f2bf(lo[1]); o[2]=f2bf(lo[2]); o[3]=f2bf(lo[3]);
    o[4]=f2bf(hi[0]); o[5]=f2bf(hi[1]); o[6]=f2bf(hi[2]); o[7]=f2bf(hi[3]);
    *reinterpret_cast<u16x8*>(smem + n * 3072 + ((gi * 16) ^ ((n & 7) << 4))) = o;
  }
  for (int g = tid; g < 4096; g += 512) {
    int n = g / 256, gi = g % 256, kc = gi * 8;
    int gr = ((n >> 2) << 10) + (wg << 2) + (n & 3);
    const float* src = (kc < 1024) ? (Whh1 + gr * 1024 + kc) : (Wxh1 + gr * 1024 + (kc - 1024));
    f32x4 lo = *reinterpret_cast<const f32x4*>(src);
    f32x4 hi = *reinterpret_cast<const f32x4*>(src + 4);
    u16x8 o;
    o[0]=f2bf(lo[0]); o[1]=f2bf(lo[1]); o[2]=f2bf(lo[2]); o[3]=f2bf(lo[3]);
    o[4]=f2bf(hi[0]); o[5]=f2bf(hi[1]); o[6]=f2bf(hi[2]); o[7]=f2bf(hi[3]);
    *reinterpret_cast<u16x8*>(smem + 49152 + n * 4096 + ((gi * 16) ^ ((n & 7) << 4))) = o;
  }
  if (tid < 16) {
    int gr = ((tid >> 2) << 10) + (wg << 2) + (tid & 3);
    bias0[tid] = bxh0[gr] + bhh0[gr];
    bias1[tid] = bxh1[gr] + bhh1[gr];
  }
  __syncthreads();

  float c0 = 0.f, c1 = 0.f;                 // register-resident cell state
  const int jcol = (wg << 2) + (tid & 3);

  for (int s = 0; s <= 512; ++s) {
    const u16* h0slot = h0seq + s * 32768;          // h0[s-1] (slot0 = zeros)
    const u16* h1prev = h1seq + (s - 1) * 32768;    // h1[s-2] (valid s>=1)
    f32x4 a0 = {0,0,0,0}, a1 = {0,0,0,0}, a2 = {0,0,0,0}, a3 = {0,0,0,0};

    // ---- pre-poll: L0 x-projection chunks (no dependence on previous step)
    if (wid < 4 && s < 512) {
      const u16* xbt = xbf + s * 16384;
      if      (wid == 0) chunks<32, 36, 32, 3072>(xbt, 512, w0, lane, a0, a1);
      else if (wid == 1) chunks<36, 40, 32, 3072>(xbt, 512, w0, lane, a0, a1);
      else if (wid == 2) chunks<40, 44, 32, 3072>(xbt, 512, w0, lane, a0, a1);
      else               chunks<44, 48, 32, 3072>(xbt, 512, w0, lane, a0, a1);
    }

    if (s >= 1) pollwait(flags, lane, s);

    // ---- post-poll: h-dependent chunks, 12 per wave (balanced)
    if (wid < 4) {
      if (s < 512) {
        if      (wid == 0) chunks<0,  8,  0, 3072>(h0slot, 1024, w0, lane, a0, a1);
        else if (wid == 1) chunks<8,  16, 0, 3072>(h0slot, 1024, w0, lane, a0, a1);
        else if (wid == 2) chunks<16, 24, 0, 3072>(h0slot, 1024, w0, lane, a0, a1);
        else               chunks<24, 32, 0, 3072>(h0slot, 1024, w0, lane, a0, a1);
      }
      if (s >= 1) {        // help layer1: 4 chunks of its h0-projection each
        if      (wid == 0) chunks<32, 36, 32, 4096>(h0slot, 1024, w1, lane, a2, a3);
        else if (wid == 1) chunks<36, 40, 32, 4096>(h0slot, 1024, w1, lane, a2, a3);
        else if (wid == 2) chunks<40, 44, 32, 4096>(h0slot, 1024, w1, lane, a2, a3);
        else               chunks<44, 48, 32, 4096>(h0slot, 1024, w1, lane, a2, a3);
      }
    } else if (s >= 1) {
      if      (wid == 4) chunks<0,  12, 0, 4096>(h1prev, 1024, w1, lane, a0, a1);
      else if (wid == 5) chunks<12, 24, 0, 4096>(h1prev, 1024, w1, lane, a0, a1);
      else if (wid == 6) { chunks<24, 32, 0, 4096>(h1prev, 1024, w1, lane, a0, a1);
                           chunks<48, 52, 32, 4096>(h0slot, 1024, w1, lane, a0, a1); }
      else               chunks<52, 64, 32, 4096>(h0slot, 1024, w1, lane, a0, a1);
    }

    // ---- partial-sum write (D-frag: col=lane&15, row=(lane>>4)*4+j)
    {
      const int n = lane & 15, br = (lane >> 4) * 4;
      if (wid < 4) {
        if (s < 512) {
#pragma unroll
          for (int j = 0; j < 4; ++j) {
            part[wid][br + j][n] = a0[j];
            part[wid][br + j + 16][n] = a1[j];
          }
        }
        if (s >= 1) {
#pragma unroll
          for (int j = 0; j < 4; ++j) {
            part[8 + wid][br + j][n] = a2[j];
            part[8 + wid][br + j + 16][n] = a3[j];
          }
        }
      } else if (s >= 1) {
#pragma unroll
        for (int j = 0; j < 4; ++j) {
          part[wid][br + j][n] = a0[j];
          part[wid][br + j + 16][n] = a1[j];
        }
      }
    }
    __syncthreads();

    if (tid < 128) {                 // ---- layer0 gates (t0 = s)
      if (s < 512) {
        const int b = tid >> 2, jj = tid & 3;
        float gs[4];
#pragma unroll
        for (int gi = 0; gi < 4; ++gi) {
          const int n = gi * 4 + jj;
          gs[gi] = part[0][b][n] + part[1][b][n] + part[2][b][n] + part[3][b][n] + bias0[n];
        }
        c0 = sgm(gs[1]) * c0 + sgm(gs[0]) * tnh(gs[2]);
        const float h = sgm(gs[3]) * tnh(c0);
        st_h_coh(h0seq + (s + 1) * 32768 + b * 1024 + jcol, h);
        if (s == 511) {
          out[HN_OFF + b * 1024 + jcol] = h;
          out[CN_OFF + b * 1024 + jcol] = c0;
        }
        asm volatile("s_waitcnt vmcnt(0)" ::: "memory");   // h at L3 before flag
      }
    } else if (tid < 256) {          // ---- layer1 gates (t1 = s-1)
      if (s >= 1) {
        const int b = (tid - 128) >> 2, jj = tid & 3;
        float gs[4];
#pragma unroll
        for (int gi = 0; gi < 4; ++gi) {
          const int n = gi * 4 + jj;
          float v = bias1[n];
#pragma unroll
          for (int p = 4; p < 12; ++p) v += part[p][b][n];
          gs[gi] = v;
        }
        c1 = sgm(gs[1]) * c1 + sgm(gs[0]) * tnh(gs[2]);
        const float h = sgm(gs[3]) * tnh(c1);
        st_h_coh(h1seq + s * 32768 + b * 1024 + jcol, h);
        const int t1 = s - 1;
        out[t1 * 32768 + b * 1024 + jcol] = h;
        if (t1 == 511) {
          out[HN_OFF + 32768 + b * 1024 + jcol] = h;
          out[CN_OFF + 32768 + b * 1024 + jcol] = c1;
        }
        asm volatile("s_waitcnt vmcnt(0)" ::: "memory");
      }
    }

    if (s == 512) break;
    __syncthreads();                 // part reads + h drains complete
    if (tid == 0)
      __hip_atomic_store(flags + wg * 16, s + 1, __ATOMIC_RELAXED, __HIP_MEMORY_SCOPE_AGENT);
  }
}

__global__ void cvt_bf16(const float* __restrict__ s, u16* __restrict__ d, int n) {
  int i = (blockIdx.x * blockDim.x + threadIdx.x) * 4;
  const int stride = gridDim.x * blockDim.x * 4;
  typedef __attribute__((ext_vector_type(4))) u16 u16x4;
  for (; i < n; i += stride) {
    f32x4 v = *reinterpret_cast<const f32x4*>(s + i);
    u16x4 o;
    o[0] = f2bf(v[0]); o[1] = f2bf(v[1]); o[2] = f2bf(v[2]); o[3] = f2bf(v[3]);
    *reinterpret_cast<u16x4*>(d + i) = o;
  }
}

// ws (bytes): xbf [0,16M) | h0seq [16777216, +513*65536) | h1seq [50397184, ..)
//             | flags [84017152, +16384)   total 84,033,536
extern "C" void kernel_launch(void* const* d_in, const int* in_sizes, int n_in,
                              void* d_out, int out_size, void* d_ws, size_t ws_size,
                              hipStream_t stream) {
  const float* x    = (const float*)d_in[0];
  const float* Wxh0 = (const float*)d_in[1];
  const float* bxh0 = (const float*)d_in[2];
  const float* Whh0 = (const float*)d_in[3];
  const float* bhh0 = (const float*)d_in[4];
  const float* Wxh1 = (const float*)d_in[5];
  const float* bxh1 = (const float*)d_in[6];
  const float* Whh1 = (const float*)d_in[7];
  const float* bhh1 = (const float*)d_in[8];
  char* ws = (char*)d_ws;
  u16* xbf   = (u16*)(ws);
  u16* h0seq = (u16*)(ws + 16777216);
  u16* h1seq = (u16*)(ws + 50397184);
  int* flags = (int*)(ws + 84017152);

  cvt_bf16<<<2048, 256, 0, stream>>>(x, xbf, 512 * 32 * 512);
  (void)hipMemsetAsync(h0seq, 0, 65536, stream);   // h0[-1] = 0
  (void)hipMemsetAsync(h1seq, 0, 65536, stream);   // h1[-1] = 0
  (void)hipMemsetAsync(flags, 0, 16384, stream);

  (void)hipFuncSetAttribute(reinterpret_cast<const void*>(lstm_fused),
                            hipFuncAttributeMaxDynamicSharedMemorySize, 140928);
  lstm_fused<<<dim3(256), dim3(512), 140928, stream>>>(
      xbf, Whh0, Wxh0, Whh1, Wxh1, bxh0, bhh0, bxh1, bhh1,
      h0seq, h1seq, flags, (float*)d_out);
}

// Round 3
// 3436.699 us; speedup vs baseline: 11.9613x; 1.3762x over previous
//
#include <hip/hip_runtime.h>

// ---------------------------------------------------------------------------
// 2-layer LSTM, T=512 B=32 I=512 H=1024 — persistent kernel, layer-pipelined.
// R3: kill the poll storm. R2 had all 8 waves polling 256 cache lines/iter of
// L3 (64B-padded flags) -> L3 contention dominated (9.2us/step, all counters
// idle). Now:
//   - flags packed: flag0[256]/flag1[256] int arrays; ONE dwordx4/lane reads
//     all 256 (16 lines). Compare >= (equality deadlocks under skew).
//   - one poller per dependency: wave0 polls flag0 (h0 ready), wave4 polls
//     flag1 (h1 ready); other waves spin on an LDS go-word (no L3 traffic).
//   - per-layer flags posted by the single gate wave right after its own
//     vmcnt(0) drain -> no extra barrier in the cross-WG critical path.
//   - A-load sharing: waves 0-3 load each h0 fragment once, feed BOTH Whh0
//     (L0) and Wxh1 (L1 x-proj) MFMAs.
// Coherence: write-once h slots, producer stores sc0|sc1 (to L3), consumer
// normal cached loads; kernel-launch acquire invalidates L2 across replays.
// ---------------------------------------------------------------------------

typedef unsigned short u16;
typedef __attribute__((ext_vector_type(8))) __bf16 bf16x8;
typedef __attribute__((ext_vector_type(8))) u16 u16x8;
typedef __attribute__((ext_vector_type(4))) float f32x4;
typedef __attribute__((ext_vector_type(2))) float f32x2;
typedef __attribute__((ext_vector_type(4))) int i32x4;
typedef __attribute__((ext_vector_type(4))) unsigned int u32x4;

#define HN_OFF 16777216   // 512*32*1024
#define CN_OFF 16842752   // HN_OFF + 2*32*1024

__device__ __forceinline__ u16 f2bf(float f) {   // RNE f32 -> bf16 (finite)
  unsigned u = __builtin_bit_cast(unsigned, f);
  u += 0x7FFFu + ((u >> 16) & 1u);
  return (u16)(u >> 16);
}
__device__ __forceinline__ float sgm(float x) { return 1.f / (1.f + __expf(-x)); }
__device__ __forceinline__ float tnh(float x) { return 2.f / (1.f + __expf(-2.f * x)) - 1.f; }

__device__ __forceinline__ bf16x8 ld16(const u16* p) {            // normal cached
  u32x4 v = *reinterpret_cast<const u32x4*>(p);
  return __builtin_bit_cast(bf16x8, v);
}
__device__ __forceinline__ bf16x8 lds16(const char* p) {
  u32x4 v = *reinterpret_cast<const u32x4*>(p);
  return __builtin_bit_cast(bf16x8, v);
}
__device__ __forceinline__ f32x4 mfma16(bf16x8 a, bf16x8 b, f32x4 c) {
  return __builtin_amdgcn_mfma_f32_16x16x32_bf16(a, b, c, 0, 0, 0);
}

// Poll: one dwordx4/lane covers all 256 flags (16 cache lines), bypass L1/L2.
__device__ __forceinline__ void pollge(const int* flags, int lane, int s) {
  const int* p = flags + (lane << 2);
  for (;;) {
    i32x4 f;
    asm volatile("global_load_dwordx4 %0, %1, off sc0 sc1\n\ts_waitcnt vmcnt(0)"
                 : "=v"(f) : "v"(p) : "memory");
    if (__all((f[0] >= s) & (f[1] >= s) & (f[2] >= s) & (f[3] >= s))) break;
  }
}

// Dual-B h0 chunk: one A-load pair feeds Whh0 (L0 accs) AND Wxh1 (L1 accs).
template <int C0, int C1>
__device__ __forceinline__ void chunks_h0(const u16* __restrict__ A,
                                          const char* w0, const char* w1, int lane,
                                          f32x4& p0, f32x4& p1, f32x4& q0, f32x4& q1) {
  const int r = lane & 15, kq = (lane >> 4) * 8, swz = (r & 7) << 4;
#pragma unroll
  for (int c = C0; c < C1; ++c) {
    const u16* ap = A + r * 1024 + c * 32 + kq;
    bf16x8 a0 = ld16(ap);
    bf16x8 a1 = ld16(ap + 16 * 1024);
    bf16x8 b0 = lds16(w0 + r * 3072 + ((c * 64 + kq * 2) ^ swz));
    bf16x8 b1 = lds16(w1 + r * 4096 + (((c + 32) * 64 + kq * 2) ^ swz));
    p0 = mfma16(a0, b0, p0);  p1 = mfma16(a1, b0, p1);
    q0 = mfma16(a0, b1, q0);  q1 = mfma16(a1, b1, q1);
  }
}
template <int C0, int C1>
__device__ __forceinline__ void chunks_h1(const u16* __restrict__ A,
                                          const char* w1, int lane,
                                          f32x4& p0, f32x4& p1) {
  const int r = lane & 15, kq = (lane >> 4) * 8, swz = (r & 7) << 4;
#pragma unroll
  for (int c = C0; c < C1; ++c) {
    const u16* ap = A + r * 1024 + c * 32 + kq;
    bf16x8 a0 = ld16(ap);
    bf16x8 a1 = ld16(ap + 16 * 1024);
    bf16x8 bw = lds16(w1 + r * 4096 + ((c * 64 + kq * 2) ^ swz));
    p0 = mfma16(a0, bw, p0);  p1 = mfma16(a1, bw, p1);
  }
}
template <int C0, int C1>
__device__ __forceinline__ void chunks_x(const u16* __restrict__ A,
                                         const char* w0, int lane,
                                         f32x4& q0, f32x4& q1) {
  const int r = lane & 15, kq = (lane >> 4) * 8, swz = (r & 7) << 4;
#pragma unroll
  for (int c = C0; c < C1; ++c) {
    const u16* ap = A + r * 512 + c * 32 + kq;
    bf16x8 a0 = ld16(ap);
    bf16x8 a1 = ld16(ap + 16 * 512);
    bf16x8 bw = lds16(w0 + r * 3072 + (((c + 32) * 64 + kq * 2) ^ swz));
    q0 = mfma16(a0, bw, q0);  q1 = mfma16(a1, bw, q1);
  }
}

// LDS (dynamic, 151744 B):
//   [0,      49152)  w0: 16 rows x 1536 bf16 [Whh0|Wxh0], XOR-swizzled
//   [49152, 114688)  w1: 16 rows x 2048 bf16 [Whh1|Wxh1], XOR-swizzled
//   [114688,151552)  part[16][32][18] f32  (0-3 L0h0, 4-7 L1h1, 8-11 L1xg, 12-15 L0x)
//   [151552]bias0[16]  [151616]bias1[16]  [151680] go[2]
__global__ __launch_bounds__(512, 2) void lstm_fused(
    const u16* __restrict__ xbf,
    const float* __restrict__ Whh0, const float* __restrict__ Wxh0,
    const float* __restrict__ Whh1, const float* __restrict__ Wxh1,
    const float* __restrict__ bxh0, const float* __restrict__ bhh0,
    const float* __restrict__ bxh1, const float* __restrict__ bhh1,
    u16* __restrict__ h0seq, u16* __restrict__ h1seq,
    int* __restrict__ flag0, int* __restrict__ flag1,
    float* __restrict__ out) {
  extern __shared__ char smem[];
  const char* w0 = smem;
  const char* w1 = smem + 49152;
  auto part = reinterpret_cast<float(*)[32][18]>(smem + 114688);
  float* bias0 = reinterpret_cast<float*>(smem + 151552);
  float* bias1 = reinterpret_cast<float*>(smem + 151616);
  volatile int* go = reinterpret_cast<volatile int*>(smem + 151680);

  const int tid = threadIdx.x;
  const int wg = blockIdx.x;
  const int wid = tid >> 6, lane = tid & 63;

  if (tid == 0) { go[0] = 0; go[1] = 0; }
  // ---- LDS weight fill, f32 -> bf16 inline (row n -> global gate*1024+wg*4+jj)
  for (int g = tid; g < 3072; g += 512) {
    int n = g / 192, gi = g % 192, kc = gi * 8;
    int gr = ((n >> 2) << 10) + (wg << 2) + (n & 3);
    const float* src = (kc < 1024) ? (Whh0 + gr * 1024 + kc) : (Wxh0 + gr * 512 + (kc - 1024));
    f32x4 lo = *reinterpret_cast<const f32x4*>(src);
    f32x4 hi = *reinterpret_cast<const f32x4*>(src + 4);
    u16x8 o;
    o[0]=f2bf(lo[0]); o[1]=f2bf(lo[1]); o[2]=f2bf(lo[2]); o[3]=f2bf(lo[3]);
    o[4]=f2bf(hi[0]); o[5]=f2bf(hi[1]); o[6]=f2bf(hi[2]); o[7]=f2bf(hi[3]);
    *reinterpret_cast<u16x8*>(smem + n * 3072 + ((gi * 16) ^ ((n & 7) << 4))) = o;
  }
  for (int g = tid; g < 4096; g += 512) {
    int n = g / 256, gi = g % 256, kc = gi * 8;
    int gr = ((n >> 2) << 10) + (wg << 2) + (n & 3);
    const float* src = (kc < 1024) ? (Whh1 + gr * 1024 + kc) : (Wxh1 + gr * 1024 + (kc - 1024));
    f32x4 lo = *reinterpret_cast<const f32x4*>(src);
    f32x4 hi = *reinterpret_cast<const f32x4*>(src + 4);
    u16x8 o;
    o[0]=f2bf(lo[0]); o[1]=f2bf(lo[1]); o[2]=f2bf(lo[2]); o[3]=f2bf(lo[3]);
    o[4]=f2bf(hi[0]); o[5]=f2bf(hi[1]); o[6]=f2bf(hi[2]); o[7]=f2bf(hi[3]);
    *reinterpret_cast<u16x8*>(smem + 49152 + n * 4096 + ((gi * 16) ^ ((n & 7) << 4))) = o;
  }
  if (tid < 16) {
    int gr = ((tid >> 2) << 10) + (wg << 2) + (tid & 3);
    bias0[tid] = bxh0[gr] + bhh0[gr];
    bias1[tid] = bxh1[gr] + bhh1[gr];
  }
  __syncthreads();

  float c0a = 0.f, c0b = 0.f, c1a = 0.f, c1b = 0.f;   // 2 cols/lane cell state
  const int bg = lane >> 1, jjb = (lane & 1) << 1;    // gate-math mapping
  const int colb = (wg << 2) + jjb;

  for (int s = 0; s <= 512; ++s) {
    const u16* h0slot = h0seq + s * 32768;          // h0[s-1] (slot0 zeros)
    const u16* h1prev = h1seq + (s - 1) * 32768;    // h1[s-2] (slot0 zeros @s=1)
    f32x4 p0 = {0,0,0,0}, p1 = {0,0,0,0}, q0 = {0,0,0,0}, q1 = {0,0,0,0};

    if (wid < 4) {
      if (s >= 1) {
        if (wid == 0) {
          pollge(flag0, lane, s);
          if (lane == 0) go[0] = s;
        } else {
          while (go[0] < s) __builtin_amdgcn_s_sleep(1);
        }
      }
      if      (wid == 0) chunks_h0<0,  8 >(h0slot, w0, w1, lane, p0, p1, q0, q1);
      else if (wid == 1) chunks_h0<8,  16>(h0slot, w0, w1, lane, p0, p1, q0, q1);
      else if (wid == 2) chunks_h0<16, 24>(h0slot, w0, w1, lane, p0, p1, q0, q1);
      else               chunks_h0<24, 32>(h0slot, w0, w1, lane, p0, p1, q0, q1);
    } else {
      const u16* xbt = xbf + s * 16384;             // x-proj: no flag dependency
      if      (wid == 4) chunks_x<0,  4 >(xbt, w0, lane, q0, q1);
      else if (wid == 5) chunks_x<4,  8 >(xbt, w0, lane, q0, q1);
      else if (wid == 6) chunks_x<8,  12>(xbt, w0, lane, q0, q1);
      else               chunks_x<12, 16>(xbt, w0, lane, q0, q1);
      if (s >= 2) {
        if (wid == 4) {
          pollge(flag1, lane, s);
          if (lane == 0) go[1] = s;
        } else {
          while (go[1] < s) __builtin_amdgcn_s_sleep(1);
        }
      }
      if      (wid == 4) chunks_h1<0,  8 >(h1prev, w1, lane, p0, p1);
      else if (wid == 5) chunks_h1<8,  16>(h1prev, w1, lane, p0, p1);
      else if (wid == 6) chunks_h1<16, 24>(h1prev, w1, lane, p0, p1);
      else               chunks_h1<24, 32>(h1prev, w1, lane, p0, p1);
    }

    {   // ---- partial-sum write (D-frag: col=lane&15, row=(lane>>4)*4+j)
      const int n = lane & 15, br = (lane >> 4) * 4;
#pragma unroll
      for (int j = 0; j < 4; ++j) {
        part[wid][br + j][n]      = p0[j];
        part[wid][br + j + 16][n] = p1[j];
        part[8 + wid][br + j][n]      = q0[j];
        part[8 + wid][br + j + 16][n] = q1[j];
      }
    }
    __syncthreads();

    if (wid == 0) {                  // ---- L0 gates (t0 = s), wave-local
      if (s < 512) {
        float v[4][2];
#pragma unroll
        for (int gi = 0; gi < 4; ++gi) {
          const int n = (gi << 2) + jjb;
          float s0 = bias0[n], s1 = bias0[n + 1];
#pragma unroll
          for (int p = 0; p < 4; ++p) {
            f32x2 a = *reinterpret_cast<const f32x2*>(&part[p][bg][n]);
            f32x2 b = *reinterpret_cast<const f32x2*>(&part[12 + p][bg][n]);
            s0 += a[0] + b[0];  s1 += a[1] + b[1];
          }
          v[gi][0] = s0; v[gi][1] = s1;
        }
        c0a = sgm(v[1][0]) * c0a + sgm(v[0][0]) * tnh(v[2][0]);
        c0b = sgm(v[1][1]) * c0b + sgm(v[0][1]) * tnh(v[2][1]);
        const float ha = sgm(v[3][0]) * tnh(c0a), hb = sgm(v[3][1]) * tnh(c0b);
        unsigned pk = (unsigned)f2bf(ha) | ((unsigned)f2bf(hb) << 16);
        u16* hp = h0seq + (s + 1) * 32768 + bg * 1024 + colb;
        asm volatile("global_store_dword %0, %1, off sc0 sc1" :: "v"(hp), "v"(pk) : "memory");
        if (s == 511) {
          *reinterpret_cast<f32x2*>(out + HN_OFF + bg * 1024 + colb) = f32x2{ha, hb};
          *reinterpret_cast<f32x2*>(out + CN_OFF + bg * 1024 + colb) = f32x2{c0a, c0b};
        }
        asm volatile("s_waitcnt vmcnt(0)" ::: "memory");
        if (lane == 0) {
          int* fp = flag0 + wg;  int fv = s + 1;
          asm volatile("global_store_dword %0, %1, off sc0 sc1" :: "v"(fp), "v"(fv) : "memory");
        }
      }
    } else if (wid == 4) {           // ---- L1 gates (t1 = s-1), wave-local
      if (s >= 1) {
        float v[4][2];
#pragma unroll
        for (int gi = 0; gi < 4; ++gi) {
          const int n = (gi << 2) + jjb;
          float s0 = bias1[n], s1 = bias1[n + 1];
#pragma unroll
          for (int p = 4; p < 12; ++p) {
            f32x2 a = *reinterpret_cast<const f32x2*>(&part[p][bg][n]);
            s0 += a[0];  s1 += a[1];
          }
          v[gi][0] = s0; v[gi][1] = s1;
        }
        c1a = sgm(v[1][0]) * c1a + sgm(v[0][0]) * tnh(v[2][0]);
        c1b = sgm(v[1][1]) * c1b + sgm(v[0][1]) * tnh(v[2][1]);
        const float ha = sgm(v[3][0]) * tnh(c1a), hb = sgm(v[3][1]) * tnh(c1b);
        unsigned pk = (unsigned)f2bf(ha) | ((unsigned)f2bf(hb) << 16);
        u16* hp = h1seq + s * 32768 + bg * 1024 + colb;
        asm volatile("global_store_dword %0, %1, off sc0 sc1" :: "v"(hp), "v"(pk) : "memory");
        const int t1 = s - 1;
        *reinterpret_cast<f32x2*>(out + t1 * 32768 + bg * 1024 + colb) = f32x2{ha, hb};
        if (t1 == 511) {
          *reinterpret_cast<f32x2*>(out + HN_OFF + 32768 + bg * 1024 + colb) = f32x2{ha, hb};
          *reinterpret_cast<f32x2*>(out + CN_OFF + 32768 + bg * 1024 + colb) = f32x2{c1a, c1b};
        }
        asm volatile("s_waitcnt vmcnt(0)" ::: "memory");
        if (lane == 0) {
          int* fp = flag1 + wg;  int fv = s + 1;
          asm volatile("global_store_dword %0, %1, off sc0 sc1" :: "v"(fp), "v"(fv) : "memory");
        }
      }
    }

    if (s == 512) break;
    __syncthreads();                 // protect part[] reuse next step
  }
}

__global__ void cvt_bf16(const float* __restrict__ s, u16* __restrict__ d, int n) {
  int i = (blockIdx.x * blockDim.x + threadIdx.x) * 4;
  const int stride = gridDim.x * blockDim.x * 4;
  typedef __attribute__((ext_vector_type(4))) u16 u16x4;
  for (; i < n; i += stride) {
    f32x4 v = *reinterpret_cast<const f32x4*>(s + i);
    u16x4 o;
    o[0] = f2bf(v[0]); o[1] = f2bf(v[1]); o[2] = f2bf(v[2]); o[3] = f2bf(v[3]);
    *reinterpret_cast<u16x4*>(d + i) = o;
  }
}

// ws (bytes): xbf [0,16M) | h0seq [16777216,+513*65536) | h1seq [50397184,+same)
//             | flag0 [84017152,1K) | flag1 [84018176,1K)   total 84,019,200
extern "C" void kernel_launch(void* const* d_in, const int* in_sizes, int n_in,
                              void* d_out, int out_size, void* d_ws, size_t ws_size,
                              hipStream_t stream) {
  const float* x    = (const float*)d_in[0];
  const float* Wxh0 = (const float*)d_in[1];
  const float* bxh0 = (const float*)d_in[2];
  const float* Whh0 = (const float*)d_in[3];
  const float* bhh0 = (const float*)d_in[4];
  const float* Wxh1 = (const float*)d_in[5];
  const float* bxh1 = (const float*)d_in[6];
  const float* Whh1 = (const float*)d_in[7];
  const float* bhh1 = (const float*)d_in[8];
  char* ws = (char*)d_ws;
  u16* xbf   = (u16*)(ws);
  u16* h0seq = (u16*)(ws + 16777216);
  u16* h1seq = (u16*)(ws + 50397184);
  int* flag0 = (int*)(ws + 84017152);
  int* flag1 = (int*)(ws + 84018176);

  cvt_bf16<<<2048, 256, 0, stream>>>(x, xbf, 512 * 32 * 512);
  (void)hipMemsetAsync(h0seq, 0, 65536, stream);   // h0[-1] = 0
  (void)hipMemsetAsync(h1seq, 0, 65536, stream);   // h1[-1] = 0
  (void)hipMemsetAsync(flag0, 0, 2048, stream);    // both flag arrays

  (void)hipFuncSetAttribute(reinterpret_cast<const void*>(lstm_fused),
                            hipFuncAttributeMaxDynamicSharedMemorySize, 151744);
  lstm_fused<<<dim3(256), dim3(512), 151744, stream>>>(
      xbf, Whh0, Wxh0, Whh1, Wxh1, bxh0, bhh0, bxh1, bhh1,
      h0seq, h1seq, flag0, flag1, (float*)d_out);
}